// Round 17
// baseline (15561.769 us; speedup 1.0000x reference)
//
#include <hip/hip_runtime.h>
#include <stdint.h>
#include <math.h>

#define V 30000
#define E 60000
#define G 1200
#define D 64
#define NODE_IN 74
#define EDGE_IN 12
#define EH 128
#define N_MP 6
#define N_S2S 6

#define NBLK ((E + 63) / 64)   // 938 edge-tiles of 64
#define EPAD (NBLK * 64)       // 60032 padded edge rows
#define GRUBLK ((V + 31) / 32) // 938 node-tiles of 32

typedef short bf16x8 __attribute__((ext_vector_type(8)));
typedef float f32x4 __attribute__((ext_vector_type(4)));

__device__ __forceinline__ float sigmoidf_(float x) {
    return 1.0f / (1.0f + __expf(-x));
}
__device__ __forceinline__ float tanhf_(float x) {
    float t = __expf(-2.0f * fabsf(x));
    float r = (1.0f - t) / (1.0f + t);
    return copysignf(r, x);
}
__device__ __forceinline__ uint16_t f2bf(float f) {
    uint32_t u = __float_as_uint(f);
    u += 0x7fffu + ((u >> 16) & 1u);
    return (uint16_t)(u >> 16);
}
__device__ __forceinline__ float bf2f(uint16_t u) {
    return __uint_as_float(((uint32_t)u) << 16);
}

// ---------------- generic zero-fill ----------------
__global__ void k_zero(float* __restrict__ p, int n4) {
    int i = blockIdx.x * blockDim.x + threadIdx.x;
    if (i < n4) ((float4*)p)[i] = make_float4(0.f, 0.f, 0.f, 0.f);
}

// ---------------- h0 = relu(node_feats @ proj_W + proj_b) ----------------
__global__ void k_node_proj(const float* __restrict__ nf, const float* __restrict__ W,
                            const float* __restrict__ b, float* __restrict__ h) {
    int wave = threadIdx.x >> 6, lane = threadIdx.x & 63;
    int v = blockIdx.x * 4 + wave;           // V % 4 == 0
    __shared__ float xs[4][NODE_IN];
    xs[wave][lane] = nf[(size_t)v * NODE_IN + lane];
    if (lane + 64 < NODE_IN) xs[wave][lane + 64] = nf[(size_t)v * NODE_IN + lane + 64];
    __syncthreads();
    float acc = b[lane];
    #pragma unroll
    for (int i = 0; i < NODE_IN; ++i) acc = fmaf(xs[wave][i], W[i * D + lane], acc);
    h[(size_t)v * D + lane] = fmaxf(acc, 0.0f);
}

// ---------------- HedgeP = bf16-permuted relu(edge_feats @ eW1 + eb1) ----------------
// Layout: chunk(b, w, kt) of 512 elems; elem (quad, m, j) = Hedge[e=b*64+w*16+m][k=kt*32+quad*8+j]
__global__ __launch_bounds__(256) void k_edge_hidden(const float* __restrict__ ef,
                              const float* __restrict__ W1,
                              const float* __restrict__ b1, uint16_t* __restrict__ HedgeP) {
    int blk = blockIdx.x;                     // EPAD/8 = 7504 blocks
    int t = threadIdx.x;
    int half = t >> 7, j = t & 127;
    __shared__ float xs[8][EDGE_IN];
    if (t < 8 * EDGE_IN) {
        int el = t / EDGE_IN, c = t % EDGE_IN;
        int e = blk * 8 + el;
        xs[el][c] = (e < E) ? ef[(size_t)e * EDGE_IN + c] : 0.f;
    }
    __syncthreads();
    #pragma unroll
    for (int l = 0; l < 4; ++l) {
        int el = half * 4 + l;
        int e = blk * 8 + el;
        float acc = b1[j];
        #pragma unroll
        for (int i = 0; i < EDGE_IN; ++i) acc = fmaf(xs[el][i], W1[i * EH + j], acc);
        float r = (e < E) ? fmaxf(acc, 0.0f) : 0.0f;
        int bb = e >> 6, ww = (e >> 4) & 3, m = e & 15;
        int kt = j >> 5, quad = (j >> 3) & 3, jj = j & 7;
        size_t off = ((((size_t)(bb * 4 + ww) * 4 + kt) * 4 + quad) * 16 + m) * 8 + jj;
        HedgeP[off] = f2bf(r);
    }
}

// ---------------- W2p: eW2 (128 x 4096 fp32) -> bf16 B-frag-permuted ----------------
// chunk(i, kt, nt) of 512; elem (quad, n0, j) = eW2[k=kt*32+quad*8+j][i*64+nt*16+n0]
__global__ void k_prep_w2(const float* __restrict__ eW2, uint16_t* __restrict__ W2p) {
    int idx = blockIdx.x * 256 + threadIdx.x;           // 524288 total
    int j = idx & 7;
    int n0 = (idx >> 3) & 15;
    int quad = (idx >> 7) & 3;
    int nt = (idx >> 9) & 3;
    int kt = (idx >> 11) & 3;
    int i = idx >> 13;
    int k = kt * 32 + quad * 8 + j;
    int col = i * 64 + nt * 16 + n0;
    W2p[idx] = f2bf(eW2[(size_t)k * 4096 + col]);
}

// ---------------- B2p: eb2 (4096,) viewed [i][o] -> bf16 B-frag-permuted ----------------
// First 4096 elems = real bias fragments; second 4096 = zeros (used by i-half 1 blocks
// so the bias-init MFMA is branch-free).
__global__ void k_prep_b2(const float* __restrict__ eb2, uint16_t* __restrict__ B2p) {
    int idx = blockIdx.x * 256 + threadIdx.x;           // 8192 total
    if (idx >= 4096) { B2p[idx] = 0; return; }
    int j = idx & 7;
    int n0 = (idx >> 3) & 15;
    int quad = (idx >> 7) & 3;
    int nt = (idx >> 9) & 3;
    int kb = (idx >> 11) & 1;
    B2p[idx] = f2bf(eb2[(size_t)(kb * 32 + quad * 8 + j) * 64 + nt * 16 + n0]);
}

// ---------------- Wcp: GRU combined weight (128 x 256) -> bf16 B-frag-permuted ----------------
// Logical Wc: rows k (0..63 = x via Wih, 64..127 = h via Whh); cols c:
//   c in [0,128):  stacked r,z gates  -> gives ir+hr (c<64) and iz+hz (64<=c<128)
//   c in [128,192): inn only (Wih cols 128..191; h rows zero)
//   c in [192,256): hn  only (Whh cols 128..191; x rows zero)
// chunk (ot*4 + kt) of 512; elem (quad, n0, j) = Wc[k=kt*32+quad*8+j][ot*16+n0]
// Also writes bc[256]: combined gate biases matching the column map.
__global__ void k_prep_wc(const float* __restrict__ Wih, const float* __restrict__ Whh,
                          const float* __restrict__ bih, const float* __restrict__ bhh,
                          uint16_t* __restrict__ Wcp, float* __restrict__ bc) {
    int idx = blockIdx.x * 256 + threadIdx.x;           // 32768 total
    int j = idx & 7;
    int n0 = (idx >> 3) & 15;
    int quad = (idx >> 7) & 3;
    int kt = (idx >> 9) & 3;
    int ot = idx >> 11;                                 // 0..15
    int k = kt * 32 + quad * 8 + j;                     // 0..127
    int c = ot * 16 + n0;                               // 0..255
    float val = 0.f;
    if (c < 128) {
        val = (k < 64) ? Wih[(size_t)k * 192 + c] : Whh[(size_t)(k - 64) * 192 + c];
    } else if (c < 192) {
        if (k < 64) val = Wih[(size_t)k * 192 + c];
    } else {
        if (k >= 64) val = Whh[(size_t)(k - 64) * 192 + (c - 64)];
    }
    Wcp[idx] = f2bf(val);
    if (idx < 256) {
        int d = idx & 63;
        float b;
        if (idx < 64)       b = bih[d] + bhh[d];
        else if (idx < 128) b = bih[64 + d] + bhh[64 + d];
        else if (idx < 192) b = bih[128 + d];
        else                b = bhh[128 + d];
        bc[idx] = b;
    }
}

// ---------------- LSTM packed weights: per-lane float4 gate rows ----------------
// WihP layout: L0 at [0,8192) float4 (din=128), L1 at [8192,12288), L2 at [12288,16384);
//   slot (i,d): float4{W[i][d], W[i][64+d], W[i][128+d], W[i][192+d]}  (i,f,g,o gates)
// WhhP layout: L0 [0,4096), L1 [4096,8192), L2 [8192,12288) — same per-slot packing.
// bc4[l*64+d] = bih_l+bhh_l packed the same way.
__global__ void k_prep_lstm(
    const float* __restrict__ Wih0, const float* __restrict__ bih0,
    const float* __restrict__ Whh0, const float* __restrict__ bhh0,
    const float* __restrict__ Wih1, const float* __restrict__ bih1,
    const float* __restrict__ Whh1, const float* __restrict__ bhh1,
    const float* __restrict__ Wih2, const float* __restrict__ bih2,
    const float* __restrict__ Whh2, const float* __restrict__ bhh2,
    float4* __restrict__ WihP, float4* __restrict__ WhhP, float4* __restrict__ bc4) {
    int idx = blockIdx.x * 256 + threadIdx.x;           // 28864 total slots
    if (idx < 16384) {
        const float* W; int base;
        if (idx < 8192)       { base = 0;     W = Wih0; }
        else if (idx < 12288) { base = 8192;  W = Wih1; }
        else                  { base = 12288; W = Wih2; }
        int local = idx - base;
        int i = local >> 6, d = local & 63;
        WihP[idx] = make_float4(W[(size_t)i * 256 + d],       W[(size_t)i * 256 + 64 + d],
                                W[(size_t)i * 256 + 128 + d], W[(size_t)i * 256 + 192 + d]);
    } else if (idx < 28672) {
        int li = idx - 16384;                           // 0..12287
        int l = li >> 12;
        int local = li & 4095;
        int k = local >> 6, d = local & 63;
        const float* W = (l == 0) ? Whh0 : (l == 1) ? Whh1 : Whh2;
        WhhP[li] = make_float4(W[(size_t)k * 256 + d],       W[(size_t)k * 256 + 64 + d],
                               W[(size_t)k * 256 + 128 + d], W[(size_t)k * 256 + 192 + d]);
    } else if (idx < 28864) {
        int bi = idx - 28672;                           // 0..191
        int l = bi >> 6, d = bi & 63;
        const float* bi_ = (l == 0) ? bih0 : (l == 1) ? bih1 : bih2;
        const float* bh_ = (l == 0) ? bhh0 : (l == 1) ? bhh1 : bhh2;
        bc4[bi] = make_float4(bi_[d] + bh_[d],             bi_[64 + d] + bh_[64 + d],
                              bi_[128 + d] + bh_[128 + d], bi_[192 + d] + bh_[192 + d]);
    }
}

// ---------------- fused We-recompute + message + scatter ----------------
// r9 structure with ONE surgical delta (r17): epilogue h-scale reads fp32 from a new
// transposed LDS array HsT via one broadcast ds_read_b128 per et (4 LDS ops + 0 cvts
// per i/wave, vs 16 ds_read_u16 + 16 cvts). HsU + bias-init + Af loads byte-identical
// to r9 (r11 failed because it ALSO rebuilt bias-init element-wise -> spill; this keeps
// bias-init untouched and adds no live register state — hv4 is consumed immediately).
__global__ __launch_bounds__(256, 3) void k_message_mfma(
    const uint16_t* __restrict__ HedgeP, const uint16_t* __restrict__ W2p,
    const uint16_t* __restrict__ B2p, const float* __restrict__ h,
    const int* __restrict__ src, const int* __restrict__ dst,
    float* __restrict__ agg) {
    const int bx = blockIdx.x;                // 2*938 blocks
    const int b = bx >> 1;
    const int ibase = (bx & 1) * 32;
    const int t = threadIdx.x;
    const int w = t >> 6, lane = t & 63;      // w = this wave's o-tile (nt)
    const int quad = lane >> 4, n0 = lane & 15;

    __shared__ uint16_t HsU[64][72];          // bf16 h rows; 144B stride keeps frags 16B-aligned
    __shared__ float HsT[64][68];             // fp32 h TRANSPOSED [i][edge-row]; 272B stride,
                                              // b128 reads at quad-uniform addrs: conflict-free
    __shared__ int srcv[64], dstv[64];

    if (t < 64) {
        int e = b * 64 + t;
        int sv = 0, dv = -1;
        if (e < E) { sv = src[e]; dv = dst[e]; }
        srcv[t] = sv; dstv[t] = dv;
    }
    __syncthreads();
    for (int idx = t; idx < 4096; idx += 256) {
        int r = idx >> 6, c = idx & 63;
        float hv = h[(size_t)srcv[r] * 64 + c];
        HsU[r][c] = f2bf(hv);
        HsT[c][r] = hv;
    }
    // A-fragments: all 4 edge-tiles x 4 K-tiles (same in every wave)
    bf16x8 Af[4][4];
    #pragma unroll
    for (int et = 0; et < 4; ++et)
        #pragma unroll
        for (int kt = 0; kt < 4; ++kt)
            Af[et][kt] = *(const bf16x8*)(HedgeP + (((size_t)(b * 4 + et) * 4 + kt) * 512) + lane * 8);
    __syncthreads();

    // ---- bias init: acc[et] = hA[et] @ b2[:, w-slice]  (zeros for i-half 1) ----
    f32x4 acc[4];
    {
        const uint16_t* b2b = B2p + (size_t)ibase * 128;   // half*4096 elems
        bf16x8 B2f0 = *(const bf16x8*)(b2b + (size_t)(0 * 4 + w) * 512 + lane * 8);
        bf16x8 B2f1 = *(const bf16x8*)(b2b + (size_t)(1 * 4 + w) * 512 + lane * 8);
        #pragma unroll
        for (int et = 0; et < 4; ++et) {
            bf16x8 hA0 = *(const bf16x8*)(&HsU[et * 16 + n0][quad * 8]);
            bf16x8 hA1 = *(const bf16x8*)(&HsU[et * 16 + n0][32 + quad * 8]);
            f32x4 z = {};
            z = __builtin_amdgcn_mfma_f32_16x16x32_bf16(hA0, B2f0, z, 0, 0, 0);
            acc[et] = __builtin_amdgcn_mfma_f32_16x16x32_bf16(hA1, B2f1, z, 0, 0, 0);
        }
    }

    // ---- main loop over this block's 32 i; 4 B-frag loads (own o-slice) per i ----
    for (int ii = 0; ii < 32; ++ii) {
        const int i = ibase + ii;
        const uint16_t* wb = W2p + (size_t)i * 8192 + lane * 8;
        bf16x8 Bf0 = *(const bf16x8*)(wb + (size_t)(0 * 4 + w) * 512);
        bf16x8 Bf1 = *(const bf16x8*)(wb + (size_t)(1 * 4 + w) * 512);
        bf16x8 Bf2 = *(const bf16x8*)(wb + (size_t)(2 * 4 + w) * 512);
        bf16x8 Bf3 = *(const bf16x8*)(wb + (size_t)(3 * 4 + w) * 512);
        #pragma unroll
        for (int et = 0; et < 4; ++et) {
            f32x4 tmp = {};
            tmp = __builtin_amdgcn_mfma_f32_16x16x32_bf16(Af[et][0], Bf0, tmp, 0, 0, 0);
            tmp = __builtin_amdgcn_mfma_f32_16x16x32_bf16(Af[et][1], Bf1, tmp, 0, 0, 0);
            tmp = __builtin_amdgcn_mfma_f32_16x16x32_bf16(Af[et][2], Bf2, tmp, 0, 0, 0);
            tmp = __builtin_amdgcn_mfma_f32_16x16x32_bf16(Af[et][3], Bf3, tmp, 0, 0, 0);
            // one 16B broadcast read: h rows r0..r0+3 of column i (quad-uniform address)
            f32x4 hv4 = *(const f32x4*)(&HsT[i][et * 16 + quad * 4]);
            acc[et][0] = fmaf(hv4[0], tmp[0], acc[et][0]);
            acc[et][1] = fmaf(hv4[1], tmp[1], acc[et][1]);
            acc[et][2] = fmaf(hv4[2], tmp[2], acc[et][2]);
            acc[et][3] = fmaf(hv4[3], tmp[3], acc[et][3]);
        }
    }

    // ---- scatter: each wave owns columns w*16..w*16+15 ----
    #pragma unroll
    for (int et = 0; et < 4; ++et) {
        #pragma unroll
        for (int reg = 0; reg < 4; ++reg) {
            int d = dstv[et * 16 + quad * 4 + reg];
            if (d >= 0)
                atomicAdd(agg + (size_t)d * 64 + w * 16 + n0, acc[et][reg]);
        }
    }
}

// ---------------- MFMA GRU: gates = [relu(agg+b)|h] @ Wc; h update; zeroes agg ----------------
// Block = 32 nodes, 4 waves; wave w owns gate columns [64w, 64w+64) (4 o-tiles).
// Gate pre-acts round-trip LDS as bf16; h update reads fp32 hcur (recurrence stays fp32).
__global__ __launch_bounds__(256) void k_gru_mfma(
    float* __restrict__ agg, const float* __restrict__ convb,
    const uint16_t* __restrict__ Wcp, const float* __restrict__ bc,
    float* __restrict__ hcur) {
    const int blk = blockIdx.x;               // GRUBLK = 938
    const int v0 = blk * 32;
    const int t = threadIdx.x;
    const int w = t >> 6, lane = t & 63;
    const int quad = lane >> 4, n0 = lane & 15;

    __shared__ uint16_t As[32][136];          // [x|h] bf16, 272B row stride (16B-aligned frags)
    __shared__ uint16_t Gs[32][264];          // gate pre-acts bf16, 528B stride

    // stage A and zero agg
    for (int idx = t; idx < 2048; idx += 256) {
        int r = idx >> 6, c = idx & 63;
        int v = v0 + r;
        if (v < V) {
            size_t off = (size_t)v * 64 + c;
            float x = fmaxf(agg[off] + convb[c], 0.f);
            agg[off] = 0.f;                   // pre-zero for next step's atomics
            As[r][c] = f2bf(x);
            As[r][64 + c] = f2bf(hcur[off]);
        } else {
            As[r][c] = 0; As[r][64 + c] = 0;
        }
    }
    __syncthreads();

    // A-fragments: 2 row-tiles x 4 K-tiles
    bf16x8 Af[2][4];
    #pragma unroll
    for (int et = 0; et < 2; ++et)
        #pragma unroll
        for (int kt = 0; kt < 4; ++kt)
            Af[et][kt] = *(const bf16x8*)(&As[et * 16 + n0][kt * 32 + quad * 8]);

    // MFMA: wave w's 4 o-tiles (cols 64w..64w+63 of 256)
    f32x4 acc[2][4] = {};
    #pragma unroll
    for (int ot4 = 0; ot4 < 4; ++ot4) {
        const uint16_t* wb = Wcp + (size_t)((w * 4 + ot4) * 4) * 512 + lane * 8;
        bf16x8 B0 = *(const bf16x8*)(wb + 0 * 512);
        bf16x8 B1 = *(const bf16x8*)(wb + 1 * 512);
        bf16x8 B2 = *(const bf16x8*)(wb + 2 * 512);
        bf16x8 B3 = *(const bf16x8*)(wb + 3 * 512);
        #pragma unroll
        for (int et = 0; et < 2; ++et) {
            f32x4 a = acc[et][ot4];
            a = __builtin_amdgcn_mfma_f32_16x16x32_bf16(Af[et][0], B0, a, 0, 0, 0);
            a = __builtin_amdgcn_mfma_f32_16x16x32_bf16(Af[et][1], B1, a, 0, 0, 0);
            a = __builtin_amdgcn_mfma_f32_16x16x32_bf16(Af[et][2], B2, a, 0, 0, 0);
            a = __builtin_amdgcn_mfma_f32_16x16x32_bf16(Af[et][3], B3, a, 0, 0, 0);
            acc[et][ot4] = a;
        }
    }
    // export gates to LDS (C-layout: col=n0, row=quad*4+reg)
    #pragma unroll
    for (int et = 0; et < 2; ++et)
        #pragma unroll
        for (int ot4 = 0; ot4 < 4; ++ot4)
            #pragma unroll
            for (int reg = 0; reg < 4; ++reg)
                Gs[et * 16 + quad * 4 + reg][(w * 4 + ot4) * 16 + n0] = f2bf(acc[et][ot4][reg]);
    __syncthreads();

    // epilogue: per (node, d)
    for (int idx = t; idx < 2048; idx += 256) {
        int r = idx >> 6, d = idx & 63;
        int v = v0 + r;
        if (v >= V) continue;
        size_t off = (size_t)v * 64 + d;
        float rp   = bf2f(Gs[r][d])        + bc[d];
        float zp   = bf2f(Gs[r][64 + d])   + bc[64 + d];
        float innv = bf2f(Gs[r][128 + d])  + bc[128 + d];
        float hnv  = bf2f(Gs[r][192 + d])  + bc[192 + d];
        float hv = hcur[off];
        float rr = sigmoidf_(rp);
        float zz = sigmoidf_(zp);
        float nn = tanhf_(innv + rr * hnv);
        hcur[off] = (1.f - zz) * nn + zz * hv;
    }
}

// ---------------- segment start offsets from sorted gids ----------------
__global__ void k_seg(const int* __restrict__ gids, int* __restrict__ start) {
    int v = blockIdx.x * blockDim.x + threadIdx.x;
    if (v > V) return;
    int cur = (v < V) ? gids[v] : G;
    int prev = (v == 0) ? -1 : gids[v - 1];
    for (int g = prev + 1; g <= cur; ++g) start[g] = v;
}

// ---------------- fused Set2Set (6 iters) + predict MLPs: ONE WAVE PER GRAPH ----------------
// EXACT r13 text — PARKED. VGPR 48, no spill, 186 us. r14 (double-buffer pipeline) and
// r15 (single-buffer 8-bursts) both spilled to scratch (FETCH 1.6-1.75 GB, >1600 us):
// on this kernel any attempt at >2 loads in flight detonates. Do not touch.
__global__ __launch_bounds__(64) void k_s2s_final(
    const float* __restrict__ h, const int* __restrict__ segs,
    const float4* __restrict__ WihP, const float4* __restrict__ WhhP,
    const float4* __restrict__ bc4,
    const float* __restrict__ pW, const float* __restrict__ pb,
    const float* __restrict__ qW1, const float* __restrict__ qb1,
    const float* __restrict__ qW2, const float* __restrict__ qb2,
    const float* __restrict__ qW3, const float* __restrict__ qb3,
    float* __restrict__ out) {
    const int g = blockIdx.x;                 // 1200 single-wave blocks
    const int lane = threadIdx.x;
    const int vs = segs[g], ve = segs[g + 1];

    float h0 = 0.f, c0 = 0.f, h1 = 0.f, c1 = 0.f, h2 = 0.f, c2 = 0.f;
    float qlo = 0.f, qhi = 0.f;               // q_star = [q | readout]
    const float4 b0 = bc4[lane], b1 = bc4[64 + lane], b2 = bc4[128 + lane];
    const float4* Wih1p = WihP + 8192;
    const float4* Wih2p = WihP + 12288;
    const float4* Whh1p = WhhP + 4096;
    const float4* Whh2p = WhhP + 8192;

    for (int s = 0; s < N_S2S; ++s) {
        // ---- layer 0 (x = q_star, din=128) ----
        float4 a = b0;
        #pragma unroll 8
        for (int i = 0; i < 64; ++i) {
            float xv = __shfl(qlo, i, 64);
            float4 wv = WihP[i * 64 + lane];
            a.x = fmaf(xv, wv.x, a.x); a.y = fmaf(xv, wv.y, a.y);
            a.z = fmaf(xv, wv.z, a.z); a.w = fmaf(xv, wv.w, a.w);
        }
        #pragma unroll 8
        for (int i = 0; i < 64; ++i) {
            float xv = __shfl(qhi, i, 64);
            float4 wv = WihP[(64 + i) * 64 + lane];
            a.x = fmaf(xv, wv.x, a.x); a.y = fmaf(xv, wv.y, a.y);
            a.z = fmaf(xv, wv.z, a.z); a.w = fmaf(xv, wv.w, a.w);
        }
        #pragma unroll 8
        for (int k = 0; k < 64; ++k) {
            float hv = __shfl(h0, k, 64);
            float4 wv = WhhP[k * 64 + lane];
            a.x = fmaf(hv, wv.x, a.x); a.y = fmaf(hv, wv.y, a.y);
            a.z = fmaf(hv, wv.z, a.z); a.w = fmaf(hv, wv.w, a.w);
        }
        c0 = sigmoidf_(a.y) * c0 + sigmoidf_(a.x) * tanhf_(a.z);
        h0 = sigmoidf_(a.w) * tanhf_(c0);
        // ---- layer 1 (x = h0) ----
        a = b1;
        #pragma unroll 8
        for (int i = 0; i < 64; ++i) {
            float xv = __shfl(h0, i, 64);
            float4 wv = Wih1p[i * 64 + lane];
            a.x = fmaf(xv, wv.x, a.x); a.y = fmaf(xv, wv.y, a.y);
            a.z = fmaf(xv, wv.z, a.z); a.w = fmaf(xv, wv.w, a.w);
        }
        #pragma unroll 8
        for (int k = 0; k < 64; ++k) {
            float hv = __shfl(h1, k, 64);
            float4 wv = Whh1p[k * 64 + lane];
            a.x = fmaf(hv, wv.x, a.x); a.y = fmaf(hv, wv.y, a.y);
            a.z = fmaf(hv, wv.z, a.z); a.w = fmaf(hv, wv.w, a.w);
        }
        c1 = sigmoidf_(a.y) * c1 + sigmoidf_(a.x) * tanhf_(a.z);
        h1 = sigmoidf_(a.w) * tanhf_(c1);
        // ---- layer 2 (x = h1) ----
        a = b2;
        #pragma unroll 8
        for (int i = 0; i < 64; ++i) {
            float xv = __shfl(h1, i, 64);
            float4 wv = Wih2p[i * 64 + lane];
            a.x = fmaf(xv, wv.x, a.x); a.y = fmaf(xv, wv.y, a.y);
            a.z = fmaf(xv, wv.z, a.z); a.w = fmaf(xv, wv.w, a.w);
        }
        #pragma unroll 8
        for (int k = 0; k < 64; ++k) {
            float hv = __shfl(h2, k, 64);
            float4 wv = Whh2p[k * 64 + lane];
            a.x = fmaf(hv, wv.x, a.x); a.y = fmaf(hv, wv.y, a.y);
            a.z = fmaf(hv, wv.z, a.z); a.w = fmaf(hv, wv.w, a.w);
        }
        c2 = sigmoidf_(a.y) * c2 + sigmoidf_(a.x) * tanhf_(a.z);
        h2 = sigmoidf_(a.w) * tanhf_(c2);
        float qd = h2;
        // ---- attention: online softmax over this graph's nodes (lane = feature) ----
        float m = -INFINITY, sden = 0.f, accd = 0.f;
        for (int v = vs; v < ve; ++v) {
            float hv = h[(size_t)v * 64 + lane];
            float p = hv * qd;
            #pragma unroll
            for (int off = 32; off > 0; off >>= 1) p += __shfl_xor(p, off, 64);
            float nm = fmaxf(m, p);
            float e1 = __expf(m - nm);        // 0 on first iteration (m = -inf)
            float e2 = __expf(p - nm);
            sden = sden * e1 + e2;
            accd = fmaf(hv, e2, accd * e1);
            m = nm;
        }
        qlo = qd;
        qhi = (ve > vs) ? accd / sden : 0.f;
    }

    // ---- predict MLPs (per-wave, register q_star) ----
    float y = pb[lane];
    #pragma unroll 8
    for (int i = 0; i < 64; ++i) y = fmaf(__shfl(qlo, i, 64), pW[i * 64 + lane], y);
    #pragma unroll 8
    for (int i = 0; i < 64; ++i) y = fmaf(__shfl(qhi, i, 64), pW[(64 + i) * 64 + lane], y);
    y = fmaxf(y, 0.f);
    float y1 = qb1[lane];
    #pragma unroll 8
    for (int i = 0; i < 64; ++i) y1 = fmaf(__shfl(y, i, 64), qW1[i * 64 + lane], y1);
    y1 = fmaxf(y1, 0.f);
    float y2 = qb2[lane];
    #pragma unroll 8
    for (int i = 0; i < 64; ++i) y2 = fmaf(__shfl(y1, i, 64), qW2[i * 64 + lane], y2);
    y2 = fmaxf(y2, 0.f);
    float p = y2 * qW3[lane];
    #pragma unroll
    for (int off = 32; off > 0; off >>= 1) p += __shfl_xor(p, off, 64);
    if (lane == 0) out[g] = p + qb3[0];
}

extern "C" void kernel_launch(void* const* d_in, const int* in_sizes, int n_in,
                              void* d_out, int out_size, void* d_ws, size_t ws_size,
                              hipStream_t stream) {
    const float* node_feats = (const float*)d_in[0];
    const float* edge_feats = (const float*)d_in[1];
    const int*   src        = (const int*)d_in[2];
    const int*   dst        = (const int*)d_in[3];
    const int*   gids       = (const int*)d_in[4];
    const float* proj_W     = (const float*)d_in[5];
    const float* proj_b     = (const float*)d_in[6];
    const float* eW1        = (const float*)d_in[7];
    const float* eb1        = (const float*)d_in[8];
    const float* eW2        = (const float*)d_in[9];
    const float* eb2        = (const float*)d_in[10];
    const float* conv_b     = (const float*)d_in[11];
    const float* gru_Wih    = (const float*)d_in[12];
    const float* gru_bih    = (const float*)d_in[13];
    const float* gru_Whh    = (const float*)d_in[14];
    const float* gru_bhh    = (const float*)d_in[15];
    const float* pW         = (const float*)d_in[16];
    const float* pb         = (const float*)d_in[17];
    const float* qW1        = (const float*)d_in[18];
    const float* qb1        = (const float*)d_in[19];
    const float* qW2        = (const float*)d_in[20];
    const float* qb2        = (const float*)d_in[21];
    const float* qW3        = (const float*)d_in[22];
    const float* qb3        = (const float*)d_in[23];
    const float* lWih0 = (const float*)d_in[24]; const float* lbih0 = (const float*)d_in[25];
    const float* lWhh0 = (const float*)d_in[26]; const float* lbhh0 = (const float*)d_in[27];
    const float* lWih1 = (const float*)d_in[28]; const float* lbih1 = (const float*)d_in[29];
    const float* lWhh1 = (const float*)d_in[30]; const float* lbhh1 = (const float*)d_in[31];
    const float* lWih2 = (const float*)d_in[32]; const float* lbih2 = (const float*)d_in[33];
    const float* lWhh2 = (const float*)d_in[34]; const float* lbhh2 = (const float*)d_in[35];

    // ---- workspace layout: within the proven 34,562,756-B footprint.
    // Wcp/bc live in the old hsbuf region; packed LSTM weights in the old csbuf region.
    char* ws = (char*)d_ws;
    uint16_t* HedgeP = (uint16_t*)(ws + 0);                      // 15,368,192 B (EPAD rows)
    uint16_t* W2p    = (uint16_t*)(ws + 15368192);               //  1,048,576 B
    uint16_t* B2p    = (uint16_t*)(ws + 16416768);               //     16,384 B (real + zero half)
    float*    hcur   = (float*)(ws + 16433152);                  //  7,680,000 B
    float*    agg    = (float*)(ws + 24113152);                  //  7,680,000 B
    int*      segs   = (int*)(ws + 34557952);                    //      4,804 B
    uint16_t* Wcp    = (uint16_t*)(ws + 32407552);               //     65,536 B
    float*    bc     = (float*)(ws + 32407552 + 65536);          //      1,024 B
    float4*   WihP   = (float4*)(ws + 33329152);                 //    262,144 B
    float4*   WhhP   = (float4*)(ws + 33591296);                 //    196,608 B
    float4*   bc4    = (float4*)(ws + 33787904);                 //      3,072 B (ends 33,790,976)

    // --- one-time phase ---
    k_node_proj<<<V / 4, 256, 0, stream>>>(node_feats, proj_W, proj_b, hcur);
    k_edge_hidden<<<EPAD / 8, 256, 0, stream>>>(edge_feats, eW1, eb1, HedgeP);
    k_prep_w2<<<2048, 256, 0, stream>>>(eW2, W2p);
    k_prep_b2<<<32, 256, 0, stream>>>(eb2, B2p);
    k_prep_wc<<<128, 256, 0, stream>>>(gru_Wih, gru_Whh, gru_bih, gru_bhh, Wcp, bc);
    k_prep_lstm<<<113, 256, 0, stream>>>(lWih0, lbih0, lWhh0, lbhh0,
                                         lWih1, lbih1, lWhh1, lbhh1,
                                         lWih2, lbih2, lWhh2, lbhh2,
                                         WihP, WhhP, bc4);
    k_seg<<<(V + 1 + 255) / 256, 256, 0, stream>>>(gids, segs);
    // zero agg once (k_gru_mfma re-zeroes it each step after consuming)
    k_zero<<<(480000 + 255) / 256, 256, 0, stream>>>(agg, 480000);  // V*64/4

    // --- message passing ---
    for (int t = 0; t < N_MP; ++t) {
        k_message_mfma<<<NBLK * 2, 256, 0, stream>>>(HedgeP, W2p, B2p, hcur, src, dst, agg);
        k_gru_mfma<<<GRUBLK, 256, 0, stream>>>(agg, conv_b, Wcp, bc, hcur);
    }

    // --- fused Set2Set + predict: one wave per graph ---
    k_s2s_final<<<G, 64, 0, stream>>>(hcur, segs, WihP, WhhP, bc4,
        pW, pb, qW1, qb1, qW2, qb2, qW3, qb3,
        (float*)d_out);
}

// Round 18
// 856.318 us; speedup vs baseline: 18.1729x; 18.1729x over previous
//
#include <hip/hip_runtime.h>
#include <stdint.h>
#include <math.h>

#define V 30000
#define E 60000
#define G 1200
#define D 64
#define NODE_IN 74
#define EDGE_IN 12
#define EH 128
#define N_MP 6
#define N_S2S 6

#define NBLK ((E + 63) / 64)   // 938 edge-tiles of 64
#define EPAD (NBLK * 64)       // 60032 padded edge rows
#define GRUBLK ((V + 31) / 32) // 938 node-tiles of 32

typedef short bf16x8 __attribute__((ext_vector_type(8)));
typedef float f32x4 __attribute__((ext_vector_type(4)));

__device__ __forceinline__ float sigmoidf_(float x) {
    return 1.0f / (1.0f + __expf(-x));
}
__device__ __forceinline__ float tanhf_(float x) {
    float t = __expf(-2.0f * fabsf(x));
    float r = (1.0f - t) / (1.0f + t);
    return copysignf(r, x);
}
__device__ __forceinline__ uint16_t f2bf(float f) {
    uint32_t u = __float_as_uint(f);
    u += 0x7fffu + ((u >> 16) & 1u);
    return (uint16_t)(u >> 16);
}
__device__ __forceinline__ float bf2f(uint16_t u) {
    return __uint_as_float(((uint32_t)u) << 16);
}

// ---------------- generic zero-fill ----------------
__global__ void k_zero(float* __restrict__ p, int n4) {
    int i = blockIdx.x * blockDim.x + threadIdx.x;
    if (i < n4) ((float4*)p)[i] = make_float4(0.f, 0.f, 0.f, 0.f);
}

// ---------------- h0 = relu(node_feats @ proj_W + proj_b) ----------------
__global__ void k_node_proj(const float* __restrict__ nf, const float* __restrict__ W,
                            const float* __restrict__ b, float* __restrict__ h) {
    int wave = threadIdx.x >> 6, lane = threadIdx.x & 63;
    int v = blockIdx.x * 4 + wave;           // V % 4 == 0
    __shared__ float xs[4][NODE_IN];
    xs[wave][lane] = nf[(size_t)v * NODE_IN + lane];
    if (lane + 64 < NODE_IN) xs[wave][lane + 64] = nf[(size_t)v * NODE_IN + lane + 64];
    __syncthreads();
    float acc = b[lane];
    #pragma unroll
    for (int i = 0; i < NODE_IN; ++i) acc = fmaf(xs[wave][i], W[i * D + lane], acc);
    h[(size_t)v * D + lane] = fmaxf(acc, 0.0f);
}

// ---------------- HedgeP = bf16-permuted relu(edge_feats @ eW1 + eb1) ----------------
// Layout: chunk(b, w, kt) of 512 elems; elem (quad, m, j) = Hedge[e=b*64+w*16+m][k=kt*32+quad*8+j]
__global__ __launch_bounds__(256) void k_edge_hidden(const float* __restrict__ ef,
                              const float* __restrict__ W1,
                              const float* __restrict__ b1, uint16_t* __restrict__ HedgeP) {
    int blk = blockIdx.x;                     // EPAD/8 = 7504 blocks
    int t = threadIdx.x;
    int half = t >> 7, j = t & 127;
    __shared__ float xs[8][EDGE_IN];
    if (t < 8 * EDGE_IN) {
        int el = t / EDGE_IN, c = t % EDGE_IN;
        int e = blk * 8 + el;
        xs[el][c] = (e < E) ? ef[(size_t)e * EDGE_IN + c] : 0.f;
    }
    __syncthreads();
    #pragma unroll
    for (int l = 0; l < 4; ++l) {
        int el = half * 4 + l;
        int e = blk * 8 + el;
        float acc = b1[j];
        #pragma unroll
        for (int i = 0; i < EDGE_IN; ++i) acc = fmaf(xs[el][i], W1[i * EH + j], acc);
        float r = (e < E) ? fmaxf(acc, 0.0f) : 0.0f;
        int bb = e >> 6, ww = (e >> 4) & 3, m = e & 15;
        int kt = j >> 5, quad = (j >> 3) & 3, jj = j & 7;
        size_t off = ((((size_t)(bb * 4 + ww) * 4 + kt) * 4 + quad) * 16 + m) * 8 + jj;
        HedgeP[off] = f2bf(r);
    }
}

// ---------------- W2p: eW2 (128 x 4096 fp32) -> bf16 B-frag-permuted ----------------
// chunk(i, kt, nt) of 512; elem (quad, n0, j) = eW2[k=kt*32+quad*8+j][i*64+nt*16+n0]
__global__ void k_prep_w2(const float* __restrict__ eW2, uint16_t* __restrict__ W2p) {
    int idx = blockIdx.x * 256 + threadIdx.x;           // 524288 total
    int j = idx & 7;
    int n0 = (idx >> 3) & 15;
    int quad = (idx >> 7) & 3;
    int nt = (idx >> 9) & 3;
    int kt = (idx >> 11) & 3;
    int i = idx >> 13;
    int k = kt * 32 + quad * 8 + j;
    int col = i * 64 + nt * 16 + n0;
    W2p[idx] = f2bf(eW2[(size_t)k * 4096 + col]);
}

// ---------------- B2p: eb2 (4096,) viewed [i][o] -> bf16 B-frag-permuted ----------------
// First 4096 elems = real bias fragments; second 4096 = zeros (used by i-half 1 blocks
// so the bias-init MFMA is branch-free).
__global__ void k_prep_b2(const float* __restrict__ eb2, uint16_t* __restrict__ B2p) {
    int idx = blockIdx.x * 256 + threadIdx.x;           // 8192 total
    if (idx >= 4096) { B2p[idx] = 0; return; }
    int j = idx & 7;
    int n0 = (idx >> 3) & 15;
    int quad = (idx >> 7) & 3;
    int nt = (idx >> 9) & 3;
    int kb = (idx >> 11) & 1;
    B2p[idx] = f2bf(eb2[(size_t)(kb * 32 + quad * 8 + j) * 64 + nt * 16 + n0]);
}

// ---------------- Wcp: GRU combined weight (128 x 256) -> bf16 B-frag-permuted ----------------
// Logical Wc: rows k (0..63 = x via Wih, 64..127 = h via Whh); cols c:
//   c in [0,128):  stacked r,z gates  -> gives ir+hr (c<64) and iz+hz (64<=c<128)
//   c in [128,192): inn only (Wih cols 128..191; h rows zero)
//   c in [192,256): hn  only (Whh cols 128..191; x rows zero)
// chunk (ot*4 + kt) of 512; elem (quad, n0, j) = Wc[k=kt*32+quad*8+j][ot*16+n0]
// Also writes bc[256]: combined gate biases matching the column map.
__global__ void k_prep_wc(const float* __restrict__ Wih, const float* __restrict__ Whh,
                          const float* __restrict__ bih, const float* __restrict__ bhh,
                          uint16_t* __restrict__ Wcp, float* __restrict__ bc) {
    int idx = blockIdx.x * 256 + threadIdx.x;           // 32768 total
    int j = idx & 7;
    int n0 = (idx >> 3) & 15;
    int quad = (idx >> 7) & 3;
    int kt = (idx >> 9) & 3;
    int ot = idx >> 11;                                 // 0..15
    int k = kt * 32 + quad * 8 + j;                     // 0..127
    int c = ot * 16 + n0;                               // 0..255
    float val = 0.f;
    if (c < 128) {
        val = (k < 64) ? Wih[(size_t)k * 192 + c] : Whh[(size_t)(k - 64) * 192 + c];
    } else if (c < 192) {
        if (k < 64) val = Wih[(size_t)k * 192 + c];
    } else {
        if (k >= 64) val = Whh[(size_t)(k - 64) * 192 + (c - 64)];
    }
    Wcp[idx] = f2bf(val);
    if (idx < 256) {
        int d = idx & 63;
        float b;
        if (idx < 64)       b = bih[d] + bhh[d];
        else if (idx < 128) b = bih[64 + d] + bhh[64 + d];
        else if (idx < 192) b = bih[128 + d];
        else                b = bhh[128 + d];
        bc[idx] = b;
    }
}

// ---------------- LSTM packed weights: per-lane float4 gate rows ----------------
// WihP layout: L0 at [0,8192) float4 (din=128), L1 at [8192,12288), L2 at [12288,16384);
//   slot (i,d): float4{W[i][d], W[i][64+d], W[i][128+d], W[i][192+d]}  (i,f,g,o gates)
// WhhP layout: L0 [0,4096), L1 [4096,8192), L2 [8192,12288) — same per-slot packing.
// bc4[l*64+d] = bih_l+bhh_l packed the same way.
__global__ void k_prep_lstm(
    const float* __restrict__ Wih0, const float* __restrict__ bih0,
    const float* __restrict__ Whh0, const float* __restrict__ bhh0,
    const float* __restrict__ Wih1, const float* __restrict__ bih1,
    const float* __restrict__ Whh1, const float* __restrict__ bhh1,
    const float* __restrict__ Wih2, const float* __restrict__ bih2,
    const float* __restrict__ Whh2, const float* __restrict__ bhh2,
    float4* __restrict__ WihP, float4* __restrict__ WhhP, float4* __restrict__ bc4) {
    int idx = blockIdx.x * 256 + threadIdx.x;           // 28864 total slots
    if (idx < 16384) {
        const float* W; int base;
        if (idx < 8192)       { base = 0;     W = Wih0; }
        else if (idx < 12288) { base = 8192;  W = Wih1; }
        else                  { base = 12288; W = Wih2; }
        int local = idx - base;
        int i = local >> 6, d = local & 63;
        WihP[idx] = make_float4(W[(size_t)i * 256 + d],       W[(size_t)i * 256 + 64 + d],
                                W[(size_t)i * 256 + 128 + d], W[(size_t)i * 256 + 192 + d]);
    } else if (idx < 28672) {
        int li = idx - 16384;                           // 0..12287
        int l = li >> 12;
        int local = li & 4095;
        int k = local >> 6, d = local & 63;
        const float* W = (l == 0) ? Whh0 : (l == 1) ? Whh1 : Whh2;
        WhhP[li] = make_float4(W[(size_t)k * 256 + d],       W[(size_t)k * 256 + 64 + d],
                               W[(size_t)k * 256 + 128 + d], W[(size_t)k * 256 + 192 + d]);
    } else if (idx < 28864) {
        int bi = idx - 28672;                           // 0..191
        int l = bi >> 6, d = bi & 63;
        const float* bi_ = (l == 0) ? bih0 : (l == 1) ? bih1 : bih2;
        const float* bh_ = (l == 0) ? bhh0 : (l == 1) ? bhh1 : bhh2;
        bc4[bi] = make_float4(bi_[d] + bh_[d],             bi_[64 + d] + bh_[64 + d],
                              bi_[128 + d] + bh_[128 + d], bi_[192 + d] + bh_[192 + d]);
    }
}

// ---------------- fused We-recompute + message + scatter (EXACT r9 text — HYPER-PARKED) ----------------
// Grid = 2*NBLK: block bx -> edge-tile b = bx>>1, i-half = bx&1 (i in [32h, 32h+32)).
// Wave w owns output columns [16w, 16w+16). Bias via MFMA against B2p (zeros for half 1).
// DO NOT TOUCH — codegen is bistable; this text = VGPR 60, Af AGPR-resident, 81 us.
// Perturbation history: r10 LDS-alias anti-remat = neutral; r11 fp32-HsT epilogue +
// rebuilt bias-init = SPILL; r17 fp32-HsT epilogue ALONE = SPILL (VGPR 84, 4.4 GB
// scratch fetch). Any epilogue/LDS change flips the allocator out of the AGPR regime.
__global__ __launch_bounds__(256, 3) void k_message_mfma(
    const uint16_t* __restrict__ HedgeP, const uint16_t* __restrict__ W2p,
    const uint16_t* __restrict__ B2p, const float* __restrict__ h,
    const int* __restrict__ src, const int* __restrict__ dst,
    float* __restrict__ agg) {
    const int bx = blockIdx.x;                // 2*938 blocks
    const int b = bx >> 1;
    const int ibase = (bx & 1) * 32;
    const int t = threadIdx.x;
    const int w = t >> 6, lane = t & 63;      // w = this wave's o-tile (nt)
    const int quad = lane >> 4, n0 = lane & 15;

    __shared__ uint16_t HsU[64][72];          // bf16 h rows; 144B stride keeps frags 16B-aligned
    __shared__ int srcv[64], dstv[64];

    if (t < 64) {
        int e = b * 64 + t;
        int sv = 0, dv = -1;
        if (e < E) { sv = src[e]; dv = dst[e]; }
        srcv[t] = sv; dstv[t] = dv;
    }
    __syncthreads();
    for (int idx = t; idx < 4096; idx += 256) {
        int r = idx >> 6, c = idx & 63;
        HsU[r][c] = f2bf(h[(size_t)srcv[r] * 64 + c]);
    }
    // A-fragments: all 4 edge-tiles x 4 K-tiles (same in every wave)
    bf16x8 Af[4][4];
    #pragma unroll
    for (int et = 0; et < 4; ++et)
        #pragma unroll
        for (int kt = 0; kt < 4; ++kt)
            Af[et][kt] = *(const bf16x8*)(HedgeP + (((size_t)(b * 4 + et) * 4 + kt) * 512) + lane * 8);
    __syncthreads();

    // ---- bias init: acc[et] = hA[et] @ b2[:, w-slice]  (zeros for i-half 1) ----
    f32x4 acc[4];
    {
        const uint16_t* b2b = B2p + (size_t)ibase * 128;   // half*4096 elems
        bf16x8 B2f0 = *(const bf16x8*)(b2b + (size_t)(0 * 4 + w) * 512 + lane * 8);
        bf16x8 B2f1 = *(const bf16x8*)(b2b + (size_t)(1 * 4 + w) * 512 + lane * 8);
        #pragma unroll
        for (int et = 0; et < 4; ++et) {
            bf16x8 hA0 = *(const bf16x8*)(&HsU[et * 16 + n0][quad * 8]);
            bf16x8 hA1 = *(const bf16x8*)(&HsU[et * 16 + n0][32 + quad * 8]);
            f32x4 z = {};
            z = __builtin_amdgcn_mfma_f32_16x16x32_bf16(hA0, B2f0, z, 0, 0, 0);
            acc[et] = __builtin_amdgcn_mfma_f32_16x16x32_bf16(hA1, B2f1, z, 0, 0, 0);
        }
    }

    // ---- main loop over this block's 32 i; 4 B-frag loads (own o-slice) per i ----
    for (int ii = 0; ii < 32; ++ii) {
        const int i = ibase + ii;
        const uint16_t* wb = W2p + (size_t)i * 8192 + lane * 8;
        bf16x8 Bf0 = *(const bf16x8*)(wb + (size_t)(0 * 4 + w) * 512);
        bf16x8 Bf1 = *(const bf16x8*)(wb + (size_t)(1 * 4 + w) * 512);
        bf16x8 Bf2 = *(const bf16x8*)(wb + (size_t)(2 * 4 + w) * 512);
        bf16x8 Bf3 = *(const bf16x8*)(wb + (size_t)(3 * 4 + w) * 512);
        #pragma unroll
        for (int et = 0; et < 4; ++et) {
            f32x4 tmp = {};
            tmp = __builtin_amdgcn_mfma_f32_16x16x32_bf16(Af[et][0], Bf0, tmp, 0, 0, 0);
            tmp = __builtin_amdgcn_mfma_f32_16x16x32_bf16(Af[et][1], Bf1, tmp, 0, 0, 0);
            tmp = __builtin_amdgcn_mfma_f32_16x16x32_bf16(Af[et][2], Bf2, tmp, 0, 0, 0);
            tmp = __builtin_amdgcn_mfma_f32_16x16x32_bf16(Af[et][3], Bf3, tmp, 0, 0, 0);
            int r0 = et * 16 + quad * 4;
            acc[et][0] = fmaf(bf2f(HsU[r0 + 0][i]), tmp[0], acc[et][0]);
            acc[et][1] = fmaf(bf2f(HsU[r0 + 1][i]), tmp[1], acc[et][1]);
            acc[et][2] = fmaf(bf2f(HsU[r0 + 2][i]), tmp[2], acc[et][2]);
            acc[et][3] = fmaf(bf2f(HsU[r0 + 3][i]), tmp[3], acc[et][3]);
        }
    }

    // ---- scatter: each wave owns columns w*16..w*16+15 ----
    #pragma unroll
    for (int et = 0; et < 4; ++et) {
        #pragma unroll
        for (int reg = 0; reg < 4; ++reg) {
            int d = dstv[et * 16 + quad * 4 + reg];
            if (d >= 0)
                atomicAdd(agg + (size_t)d * 64 + w * 16 + n0, acc[et][reg]);
        }
    }
}

// ---------------- MFMA GRU: gates = [relu(agg+b)|h] @ Wc; h update; zeroes agg ----------------
// Block = 32 nodes, 4 waves; wave w owns gate columns [64w, 64w+64) (4 o-tiles).
// Gate pre-acts round-trip LDS as bf16; h update reads fp32 hcur (recurrence stays fp32).
__global__ __launch_bounds__(256) void k_gru_mfma(
    float* __restrict__ agg, const float* __restrict__ convb,
    const uint16_t* __restrict__ Wcp, const float* __restrict__ bc,
    float* __restrict__ hcur) {
    const int blk = blockIdx.x;               // GRUBLK = 938
    const int v0 = blk * 32;
    const int t = threadIdx.x;
    const int w = t >> 6, lane = t & 63;
    const int quad = lane >> 4, n0 = lane & 15;

    __shared__ uint16_t As[32][136];          // [x|h] bf16, 272B row stride (16B-aligned frags)
    __shared__ uint16_t Gs[32][264];          // gate pre-acts bf16, 528B stride

    // stage A and zero agg
    for (int idx = t; idx < 2048; idx += 256) {
        int r = idx >> 6, c = idx & 63;
        int v = v0 + r;
        if (v < V) {
            size_t off = (size_t)v * 64 + c;
            float x = fmaxf(agg[off] + convb[c], 0.f);
            agg[off] = 0.f;                   // pre-zero for next step's atomics
            As[r][c] = f2bf(x);
            As[r][64 + c] = f2bf(hcur[off]);
        } else {
            As[r][c] = 0; As[r][64 + c] = 0;
        }
    }
    __syncthreads();

    // A-fragments: 2 row-tiles x 4 K-tiles
    bf16x8 Af[2][4];
    #pragma unroll
    for (int et = 0; et < 2; ++et)
        #pragma unroll
        for (int kt = 0; kt < 4; ++kt)
            Af[et][kt] = *(const bf16x8*)(&As[et * 16 + n0][kt * 32 + quad * 8]);

    // MFMA: wave w's 4 o-tiles (cols 64w..64w+63 of 256)
    f32x4 acc[2][4] = {};
    #pragma unroll
    for (int ot4 = 0; ot4 < 4; ++ot4) {
        const uint16_t* wb = Wcp + (size_t)((w * 4 + ot4) * 4) * 512 + lane * 8;
        bf16x8 B0 = *(const bf16x8*)(wb + 0 * 512);
        bf16x8 B1 = *(const bf16x8*)(wb + 1 * 512);
        bf16x8 B2 = *(const bf16x8*)(wb + 2 * 512);
        bf16x8 B3 = *(const bf16x8*)(wb + 3 * 512);
        #pragma unroll
        for (int et = 0; et < 2; ++et) {
            f32x4 a = acc[et][ot4];
            a = __builtin_amdgcn_mfma_f32_16x16x32_bf16(Af[et][0], B0, a, 0, 0, 0);
            a = __builtin_amdgcn_mfma_f32_16x16x32_bf16(Af[et][1], B1, a, 0, 0, 0);
            a = __builtin_amdgcn_mfma_f32_16x16x32_bf16(Af[et][2], B2, a, 0, 0, 0);
            a = __builtin_amdgcn_mfma_f32_16x16x32_bf16(Af[et][3], B3, a, 0, 0, 0);
            acc[et][ot4] = a;
        }
    }
    // export gates to LDS (C-layout: col=n0, row=quad*4+reg)
    #pragma unroll
    for (int et = 0; et < 2; ++et)
        #pragma unroll
        for (int ot4 = 0; ot4 < 4; ++ot4)
            #pragma unroll
            for (int reg = 0; reg < 4; ++reg)
                Gs[et * 16 + quad * 4 + reg][(w * 4 + ot4) * 16 + n0] = f2bf(acc[et][ot4][reg]);
    __syncthreads();

    // epilogue: per (node, d)
    for (int idx = t; idx < 2048; idx += 256) {
        int r = idx >> 6, d = idx & 63;
        int v = v0 + r;
        if (v >= V) continue;
        size_t off = (size_t)v * 64 + d;
        float rp   = bf2f(Gs[r][d])        + bc[d];
        float zp   = bf2f(Gs[r][64 + d])   + bc[64 + d];
        float innv = bf2f(Gs[r][128 + d])  + bc[128 + d];
        float hnv  = bf2f(Gs[r][192 + d])  + bc[192 + d];
        float hv = hcur[off];
        float rr = sigmoidf_(rp);
        float zz = sigmoidf_(zp);
        float nn = tanhf_(innv + rr * hnv);
        hcur[off] = (1.f - zz) * nn + zz * hv;
    }
}

// ---------------- segment start offsets from sorted gids ----------------
__global__ void k_seg(const int* __restrict__ gids, int* __restrict__ start) {
    int v = blockIdx.x * blockDim.x + threadIdx.x;
    if (v > V) return;
    int cur = (v < V) ? gids[v] : G;
    int prev = (v == 0) ? -1 : gids[v - 1];
    for (int g = prev + 1; g <= cur; ++g) start[g] = v;
}

// ---------------- fused Set2Set (6 iters) + predict MLPs: ONE WAVE PER GRAPH ----------------
// EXACT r13 text — PARKED. VGPR 48, no spill, 186 us. r14 (double-buffer pipeline) and
// r15 (single-buffer 8-bursts) both spilled to scratch (FETCH 1.6-1.75 GB, >1600 us):
// on this kernel any attempt at >2 loads in flight detonates. Do not touch.
__global__ __launch_bounds__(64) void k_s2s_final(
    const float* __restrict__ h, const int* __restrict__ segs,
    const float4* __restrict__ WihP, const float4* __restrict__ WhhP,
    const float4* __restrict__ bc4,
    const float* __restrict__ pW, const float* __restrict__ pb,
    const float* __restrict__ qW1, const float* __restrict__ qb1,
    const float* __restrict__ qW2, const float* __restrict__ qb2,
    const float* __restrict__ qW3, const float* __restrict__ qb3,
    float* __restrict__ out) {
    const int g = blockIdx.x;                 // 1200 single-wave blocks
    const int lane = threadIdx.x;
    const int vs = segs[g], ve = segs[g + 1];

    float h0 = 0.f, c0 = 0.f, h1 = 0.f, c1 = 0.f, h2 = 0.f, c2 = 0.f;
    float qlo = 0.f, qhi = 0.f;               // q_star = [q | readout]
    const float4 b0 = bc4[lane], b1 = bc4[64 + lane], b2 = bc4[128 + lane];
    const float4* Wih1p = WihP + 8192;
    const float4* Wih2p = WihP + 12288;
    const float4* Whh1p = WhhP + 4096;
    const float4* Whh2p = WhhP + 8192;

    for (int s = 0; s < N_S2S; ++s) {
        // ---- layer 0 (x = q_star, din=128) ----
        float4 a = b0;
        #pragma unroll 8
        for (int i = 0; i < 64; ++i) {
            float xv = __shfl(qlo, i, 64);
            float4 wv = WihP[i * 64 + lane];
            a.x = fmaf(xv, wv.x, a.x); a.y = fmaf(xv, wv.y, a.y);
            a.z = fmaf(xv, wv.z, a.z); a.w = fmaf(xv, wv.w, a.w);
        }
        #pragma unroll 8
        for (int i = 0; i < 64; ++i) {
            float xv = __shfl(qhi, i, 64);
            float4 wv = WihP[(64 + i) * 64 + lane];
            a.x = fmaf(xv, wv.x, a.x); a.y = fmaf(xv, wv.y, a.y);
            a.z = fmaf(xv, wv.z, a.z); a.w = fmaf(xv, wv.w, a.w);
        }
        #pragma unroll 8
        for (int k = 0; k < 64; ++k) {
            float hv = __shfl(h0, k, 64);
            float4 wv = WhhP[k * 64 + lane];
            a.x = fmaf(hv, wv.x, a.x); a.y = fmaf(hv, wv.y, a.y);
            a.z = fmaf(hv, wv.z, a.z); a.w = fmaf(hv, wv.w, a.w);
        }
        c0 = sigmoidf_(a.y) * c0 + sigmoidf_(a.x) * tanhf_(a.z);
        h0 = sigmoidf_(a.w) * tanhf_(c0);
        // ---- layer 1 (x = h0) ----
        a = b1;
        #pragma unroll 8
        for (int i = 0; i < 64; ++i) {
            float xv = __shfl(h0, i, 64);
            float4 wv = Wih1p[i * 64 + lane];
            a.x = fmaf(xv, wv.x, a.x); a.y = fmaf(xv, wv.y, a.y);
            a.z = fmaf(xv, wv.z, a.z); a.w = fmaf(xv, wv.w, a.w);
        }
        #pragma unroll 8
        for (int k = 0; k < 64; ++k) {
            float hv = __shfl(h1, k, 64);
            float4 wv = Whh1p[k * 64 + lane];
            a.x = fmaf(hv, wv.x, a.x); a.y = fmaf(hv, wv.y, a.y);
            a.z = fmaf(hv, wv.z, a.z); a.w = fmaf(hv, wv.w, a.w);
        }
        c1 = sigmoidf_(a.y) * c1 + sigmoidf_(a.x) * tanhf_(a.z);
        h1 = sigmoidf_(a.w) * tanhf_(c1);
        // ---- layer 2 (x = h1) ----
        a = b2;
        #pragma unroll 8
        for (int i = 0; i < 64; ++i) {
            float xv = __shfl(h1, i, 64);
            float4 wv = Wih2p[i * 64 + lane];
            a.x = fmaf(xv, wv.x, a.x); a.y = fmaf(xv, wv.y, a.y);
            a.z = fmaf(xv, wv.z, a.z); a.w = fmaf(xv, wv.w, a.w);
        }
        #pragma unroll 8
        for (int k = 0; k < 64; ++k) {
            float hv = __shfl(h2, k, 64);
            float4 wv = Whh2p[k * 64 + lane];
            a.x = fmaf(hv, wv.x, a.x); a.y = fmaf(hv, wv.y, a.y);
            a.z = fmaf(hv, wv.z, a.z); a.w = fmaf(hv, wv.w, a.w);
        }
        c2 = sigmoidf_(a.y) * c2 + sigmoidf_(a.x) * tanhf_(a.z);
        h2 = sigmoidf_(a.w) * tanhf_(c2);
        float qd = h2;
        // ---- attention: online softmax over this graph's nodes (lane = feature) ----
        float m = -INFINITY, sden = 0.f, accd = 0.f;
        for (int v = vs; v < ve; ++v) {
            float hv = h[(size_t)v * 64 + lane];
            float p = hv * qd;
            #pragma unroll
            for (int off = 32; off > 0; off >>= 1) p += __shfl_xor(p, off, 64);
            float nm = fmaxf(m, p);
            float e1 = __expf(m - nm);        // 0 on first iteration (m = -inf)
            float e2 = __expf(p - nm);
            sden = sden * e1 + e2;
            accd = fmaf(hv, e2, accd * e1);
            m = nm;
        }
        qlo = qd;
        qhi = (ve > vs) ? accd / sden : 0.f;
    }

    // ---- predict MLPs (per-wave, register q_star) ----
    float y = pb[lane];
    #pragma unroll 8
    for (int i = 0; i < 64; ++i) y = fmaf(__shfl(qlo, i, 64), pW[i * 64 + lane], y);
    #pragma unroll 8
    for (int i = 0; i < 64; ++i) y = fmaf(__shfl(qhi, i, 64), pW[(64 + i) * 64 + lane], y);
    y = fmaxf(y, 0.f);
    float y1 = qb1[lane];
    #pragma unroll 8
    for (int i = 0; i < 64; ++i) y1 = fmaf(__shfl(y, i, 64), qW1[i * 64 + lane], y1);
    y1 = fmaxf(y1, 0.f);
    float y2 = qb2[lane];
    #pragma unroll 8
    for (int i = 0; i < 64; ++i) y2 = fmaf(__shfl(y1, i, 64), qW2[i * 64 + lane], y2);
    y2 = fmaxf(y2, 0.f);
    float p = y2 * qW3[lane];
    #pragma unroll
    for (int off = 32; off > 0; off >>= 1) p += __shfl_xor(p, off, 64);
    if (lane == 0) out[g] = p + qb3[0];
}

extern "C" void kernel_launch(void* const* d_in, const int* in_sizes, int n_in,
                              void* d_out, int out_size, void* d_ws, size_t ws_size,
                              hipStream_t stream) {
    const float* node_feats = (const float*)d_in[0];
    const float* edge_feats = (const float*)d_in[1];
    const int*   src        = (const int*)d_in[2];
    const int*   dst        = (const int*)d_in[3];
    const int*   gids       = (const int*)d_in[4];
    const float* proj_W     = (const float*)d_in[5];
    const float* proj_b     = (const float*)d_in[6];
    const float* eW1        = (const float*)d_in[7];
    const float* eb1        = (const float*)d_in[8];
    const float* eW2        = (const float*)d_in[9];
    const float* eb2        = (const float*)d_in[10];
    const float* conv_b     = (const float*)d_in[11];
    const float* gru_Wih    = (const float*)d_in[12];
    const float* gru_bih    = (const float*)d_in[13];
    const float* gru_Whh    = (const float*)d_in[14];
    const float* gru_bhh    = (const float*)d_in[15];
    const float* pW         = (const float*)d_in[16];
    const float* pb         = (const float*)d_in[17];
    const float* qW1        = (const float*)d_in[18];
    const float* qb1        = (const float*)d_in[19];
    const float* qW2        = (const float*)d_in[20];
    const float* qb2        = (const float*)d_in[21];
    const float* qW3        = (const float*)d_in[22];
    const float* qb3        = (const float*)d_in[23];
    const float* lWih0 = (const float*)d_in[24]; const float* lbih0 = (const float*)d_in[25];
    const float* lWhh0 = (const float*)d_in[26]; const float* lbhh0 = (const float*)d_in[27];
    const float* lWih1 = (const float*)d_in[28]; const float* lbih1 = (const float*)d_in[29];
    const float* lWhh1 = (const float*)d_in[30]; const float* lbhh1 = (const float*)d_in[31];
    const float* lWih2 = (const float*)d_in[32]; const float* lbih2 = (const float*)d_in[33];
    const float* lWhh2 = (const float*)d_in[34]; const float* lbhh2 = (const float*)d_in[35];

    // ---- workspace layout: within the proven 34,562,756-B footprint.
    // Wcp/bc live in the old hsbuf region; packed LSTM weights in the old csbuf region.
    char* ws = (char*)d_ws;
    uint16_t* HedgeP = (uint16_t*)(ws + 0);                      // 15,368,192 B (EPAD rows)
    uint16_t* W2p    = (uint16_t*)(ws + 15368192);               //  1,048,576 B
    uint16_t* B2p    = (uint16_t*)(ws + 16416768);               //     16,384 B (real + zero half)
    float*    hcur   = (float*)(ws + 16433152);                  //  7,680,000 B
    float*    agg    = (float*)(ws + 24113152);                  //  7,680,000 B
    int*      segs   = (int*)(ws + 34557952);                    //      4,804 B
    uint16_t* Wcp    = (uint16_t*)(ws + 32407552);               //     65,536 B
    float*    bc     = (float*)(ws + 32407552 + 65536);          //      1,024 B
    float4*   WihP   = (float4*)(ws + 33329152);                 //    262,144 B
    float4*   WhhP   = (float4*)(ws + 33591296);                 //    196,608 B
    float4*   bc4    = (float4*)(ws + 33787904);                 //      3,072 B (ends 33,790,976)

    // --- one-time phase ---
    k_node_proj<<<V / 4, 256, 0, stream>>>(node_feats, proj_W, proj_b, hcur);
    k_edge_hidden<<<EPAD / 8, 256, 0, stream>>>(edge_feats, eW1, eb1, HedgeP);
    k_prep_w2<<<2048, 256, 0, stream>>>(eW2, W2p);
    k_prep_b2<<<32, 256, 0, stream>>>(eb2, B2p);
    k_prep_wc<<<128, 256, 0, stream>>>(gru_Wih, gru_Whh, gru_bih, gru_bhh, Wcp, bc);
    k_prep_lstm<<<113, 256, 0, stream>>>(lWih0, lbih0, lWhh0, lbhh0,
                                         lWih1, lbih1, lWhh1, lbhh1,
                                         lWih2, lbih2, lWhh2, lbhh2,
                                         WihP, WhhP, bc4);
    k_seg<<<(V + 1 + 255) / 256, 256, 0, stream>>>(gids, segs);
    // zero agg once (k_gru_mfma re-zeroes it each step after consuming)
    k_zero<<<(480000 + 255) / 256, 256, 0, stream>>>(agg, 480000);  // V*64/4

    // --- message passing ---
    for (int t = 0; t < N_MP; ++t) {
        k_message_mfma<<<NBLK * 2, 256, 0, stream>>>(HedgeP, W2p, B2p, hcur, src, dst, agg);
        k_gru_mfma<<<GRUBLK, 256, 0, stream>>>(agg, conv_b, Wcp, bc, hcur);
    }

    // --- fused Set2Set + predict: one wave per graph ---
    k_s2s_final<<<G, 64, 0, stream>>>(hcur, segs, WihP, WhhP, bc4,
        pW, pb, qW1, qb1, qW2, qb2, qW3, qb3,
        (float*)d_out);
}